// Round 6
// baseline (133.970 us; speedup 1.0000x reference)
//
#include <hip/hip_runtime.h>

typedef __bf16 bf16_t;
typedef bf16_t bf16x8 __attribute__((ext_vector_type(8)));
typedef bf16_t bf16x4 __attribute__((ext_vector_type(4)));
typedef float f32x4 __attribute__((ext_vector_type(4)));

#define HW 4096
#define NC 256

__device__ __forceinline__ f32x4 mfma16(bf16x8 a, bf16x8 b, f32x4 c) {
  return __builtin_amdgcn_mfma_f32_16x16x32_bf16(a, b, c, 0, 0, 0);
}

// ---------------- kernel 0: convert weights fp32 -> bf16 ----------------
__global__ void cvt_w(const float* __restrict__ wq, const float* __restrict__ wk,
                      const float* __restrict__ wv, const float* __restrict__ wo,
                      bf16_t* __restrict__ dst) {
  int i = blockIdx.x * 256 + threadIdx.x;           // 65536 threads
  dst[i]          = (bf16_t)wq[i];
  dst[65536 + i]  = (bf16_t)wk[i];
  dst[131072 + i] = (bf16_t)wv[i];
  dst[196608 + i] = (bf16_t)wo[i];
}

// ---------------- kernel 1: QKV projection ----------------
// grid (64 p-tiles, 4 o-tiles, 2 b), block 256 (4 waves)
// Q,K stored [b][h][p][d] bf16 (Q pre-scaled by dk^-0.5 * log2(e)); V stored [b][o][p] bf16.
__global__ __launch_bounds__(256) void proj_qkv(
    const float* __restrict__ x, const float* __restrict__ flu,
    const bf16_t* __restrict__ Wq, const bf16_t* __restrict__ Wk,
    const bf16_t* __restrict__ Wv,
    const float* __restrict__ bq, const float* __restrict__ bk,
    const float* __restrict__ bv,
    bf16_t* __restrict__ Qb, bf16_t* __restrict__ Kb, bf16_t* __restrict__ Vb) {
  const int p0 = blockIdx.x * 64;
  const int o0 = blockIdx.y * 64;
  const int b  = blockIdx.z;
  const int tid = threadIdx.x;
  const int w = tid >> 6;
  const int lane = tid & 63;
  const int ln = lane & 15, hi = lane >> 4;

  __shared__ __align__(16) bf16_t lds_f[64][40];   // [p][c], pad 32->40
  __shared__ __align__(16) bf16_t lds_x[64][40];

  f32x4 accQ[4] = {}, accK[4] = {}, accV[4] = {};

  const int cl = tid >> 3;          // 0..31 local c
  const int pp = (tid & 7) * 4;     // 0..28 local p
  const float* fbase = flu + (size_t)b * NC * HW + p0;
  const float* xbase = x   + (size_t)b * NC * HW + p0;

  for (int c0 = 0; c0 < NC; c0 += 32) {
    __syncthreads();
    {
      const float* fr = fbase + (size_t)(c0 + cl) * HW;
      const float* xr = xbase + (size_t)(c0 + cl) * HW;
      float4 fa = *(const float4*)(fr + pp);
      float4 fb = *(const float4*)(fr + pp + 32);
      float4 xa = *(const float4*)(xr + pp);
      float4 xb = *(const float4*)(xr + pp + 32);
      lds_f[pp + 0][cl] = (bf16_t)fa.x;  lds_f[pp + 1][cl] = (bf16_t)fa.y;
      lds_f[pp + 2][cl] = (bf16_t)fa.z;  lds_f[pp + 3][cl] = (bf16_t)fa.w;
      lds_f[pp + 32][cl] = (bf16_t)fb.x; lds_f[pp + 33][cl] = (bf16_t)fb.y;
      lds_f[pp + 34][cl] = (bf16_t)fb.z; lds_f[pp + 35][cl] = (bf16_t)fb.w;
      lds_x[pp + 0][cl] = (bf16_t)xa.x;  lds_x[pp + 1][cl] = (bf16_t)xa.y;
      lds_x[pp + 2][cl] = (bf16_t)xa.z;  lds_x[pp + 3][cl] = (bf16_t)xa.w;
      lds_x[pp + 32][cl] = (bf16_t)xb.x; lds_x[pp + 33][cl] = (bf16_t)xb.y;
      lds_x[pp + 34][cl] = (bf16_t)xb.z; lds_x[pp + 35][cl] = (bf16_t)xb.w;
    }
    __syncthreads();

    bf16x8 af = *(const bf16x8*)&lds_f[w * 16 + ln][hi * 8];
    bf16x8 ax = *(const bf16x8*)&lds_x[w * 16 + ln][hi * 8];
    bf16x8 awv = *(const bf16x8*)(Wv + (size_t)(o0 + w * 16 + ln) * NC + c0 + hi * 8);
#pragma unroll
    for (int t = 0; t < 4; ++t) {
      bf16x8 bwq = *(const bf16x8*)(Wq + (size_t)(o0 + t * 16 + ln) * NC + c0 + hi * 8);
      accQ[t] = mfma16(af, bwq, accQ[t]);
      bf16x8 bwk = *(const bf16x8*)(Wk + (size_t)(o0 + t * 16 + ln) * NC + c0 + hi * 8);
      accK[t] = mfma16(ax, bwk, accK[t]);
      bf16x8 bx = *(const bf16x8*)&lds_x[t * 16 + ln][hi * 8];
      accV[t] = mfma16(awv, bx, accV[t]);
    }
  }

  // dk^-0.5 * log2(e): exp2-domain logits
  const float scale = 0.17677669529663687f * 1.4426950408889634f;
#pragma unroll
  for (int t = 0; t < 4; ++t) {
    int o = o0 + t * 16 + ln;
    int h = o >> 5, d = o & 31;
    float bqv = bq[o], bkv = bk[o];
#pragma unroll
    for (int r = 0; r < 4; ++r) {
      int p = p0 + w * 16 + hi * 4 + r;
      size_t idx = (((size_t)(b * 8 + h)) * HW + p) * 32 + d;
      Qb[idx] = (bf16_t)((accQ[t][r] + bqv) * scale);
      Kb[idx] = (bf16_t)(accK[t][r] + bkv);
    }
  }
#pragma unroll
  for (int t = 0; t < 4; ++t) {
    int p = p0 + t * 16 + ln;
#pragma unroll
    for (int r = 0; r < 4; ++r) {
      int o = o0 + w * 16 + hi * 4 + r;
      Vb[((size_t)b * NC + o) * HW + p] = (bf16_t)(accV[t][r] + bv[o]);
    }
  }
}

// ---------------- kernel 2: flash attention ----------------
// Swapped QK^T with PERMUTED key rows: A-row ln of QK-mfma j holds key
// F_j(ln) = 8*(ln>>2) + (ln&3) + 4j, so lane (ln,hi) receives S for keys
// 8hi+4j+r == the exact bf16x8 B-fragment of the PV mfma. P stays in
// registers (exp2 -> cvt -> mfma); no LDS round-trip, no extra shuffles.
// No-max softmax (|logit|<1 by construction), conflict-free XOR swizzles,
// reg-staged double buffer, 1 barrier/tile. LDS = 16KB.
// grid 1024 XCD-swizzled; block 256 (4 waves, 16 q-rows each).
__global__ __launch_bounds__(256, 4) void attn_fwd(
    const bf16_t* __restrict__ Qb, const bf16_t* __restrict__ Kb,
    const bf16_t* __restrict__ Vb, bf16_t* __restrict__ AO) {
  // bijective XCD swizzle: 1024 blocks, each XCD gets 128 contiguous lids = 2 bh
  const int fid = blockIdx.y * 64 + blockIdx.x;
  const int lid = (fid & 7) * 128 + (fid >> 3);
  const int q0 = (lid & 63) * 64;
  const int bh = lid >> 6;
  const int b = bh >> 3, h = bh & 7;
  const int tid = threadIdx.x;
  const int w = tid >> 6, lane = tid & 63;
  const int ln = lane & 15, hi = lane >> 4;

  __shared__ __align__(16) bf16_t Kt[2][64 * 32];   // [m][d], swz slot^((m>>1)&3)
  __shared__ __align__(16) bf16_t Vt[2][32 * 64];   // [d][m], swz slot^(d&7)

  const bf16_t* Qh = Qb + (size_t)bh * HW * 32;
  const bf16_t* Kh = Kb + (size_t)bh * HW * 32;
  const bf16_t* Vh = Vb + ((size_t)b * NC + h * 32) * HW;

  // B-frag of Q^T: lane holds Q[q0 + w*16 + ln][hi*8..+7]
  const bf16x8 qf = *(const bf16x8*)(Qh + (size_t)(q0 + w * 16 + ln) * 32 + hi * 8);

  f32x4 O[2] = {};              // O^T accum [dt], lane owns q-col ln
  float lsum0 = 0.f, lsum1 = 0.f;

  // staging (256 threads): K 64x32 (1x16B/thread), V^T 32x64 (1x16B/thread)
  const int kr = tid >> 2, ks = tid & 3;
  const int kofs = kr * 32 + ((ks ^ ((kr >> 1) & 3)) * 8);
  const bf16_t* kgp = Kh + kr * 32 + ks * 8;
  const int vr = tid >> 3, vs = tid & 7;
  const int vofs = vr * 64 + ((vs ^ (vr & 7)) * 8);
  const bf16_t* vgp = Vh + (size_t)vr * HW + vs * 8;

  // permuted, conflict-free K read offsets: kread[ch][j], j = QK-mfma index
  int kread[2][2], vread[2][2];
  {
    const int F0 = 8 * (ln >> 2) + (ln & 3);
    const int F1 = F0 + 4;
    const int s0 = (F0 >> 1) & 3;
    const int s1 = (F1 >> 1) & 3;
#pragma unroll
    for (int ch = 0; ch < 2; ++ch) {
      kread[ch][0] = (ch * 32 + F0) * 32 + ((hi ^ s0) * 8);
      kread[ch][1] = (ch * 32 + F1) * 32 + ((hi ^ s1) * 8);
    }
  }
#pragma unroll
  for (int dt = 0; dt < 2; ++dt)
#pragma unroll
    for (int ch = 0; ch < 2; ++ch)
      vread[dt][ch] = (dt * 16 + ln) * 64 + (((ch * 4 + hi) ^ (ln & 7)) * 8);

  // prologue: tile 0 in regs
  bf16x8 krv = *(const bf16x8*)kgp;
  bf16x8 vrv = *(const bf16x8*)vgp;

  for (int it = 0; it < 64; ++it) {
    bf16_t* K_ = Kt[it & 1];
    bf16_t* V_ = Vt[it & 1];
    *(bf16x8*)&K_[kofs] = krv;
    *(bf16x8*)&V_[vofs] = vrv;
    __syncthreads();
    if (it < 63) {                       // prefetch next tile (hidden under compute)
      krv = *(const bf16x8*)(kgp + (size_t)(it + 1) * 2048);
      vrv = *(const bf16x8*)(vgp + (it + 1) * 64);
    }
#pragma unroll
    for (int ch = 0; ch < 2; ++ch) {
      // S^T = K Q^T with permuted key rows: S[j][r] = P-logit[key 8hi+4j+r][q=ln]
      bf16x8 kf0 = *(const bf16x8*)&K_[kread[ch][0]];
      bf16x8 kf1 = *(const bf16x8*)&K_[kread[ch][1]];
      f32x4 z = {};
      f32x4 S0 = mfma16(kf0, qf, z);
      f32x4 S1 = mfma16(kf1, qf, z);
      // P = exp2(S) (no max shift needed), partial denominators
      float e00 = exp2f(S0[0]), e01 = exp2f(S0[1]);
      float e02 = exp2f(S0[2]), e03 = exp2f(S0[3]);
      float e10 = exp2f(S1[0]), e11 = exp2f(S1[1]);
      float e12 = exp2f(S1[2]), e13 = exp2f(S1[3]);
      lsum0 += (e00 + e01) + (e02 + e03);
      lsum1 += (e10 + e11) + (e12 + e13);
      // register-direct PV B-fragment: keys 8hi..8hi+7 for q=ln
      bf16x8 pf = {(bf16_t)e00, (bf16_t)e01, (bf16_t)e02, (bf16_t)e03,
                   (bf16_t)e10, (bf16_t)e11, (bf16_t)e12, (bf16_t)e13};
      // O^T += V^T P^T
#pragma unroll
      for (int dt = 0; dt < 2; ++dt) {
        bf16x8 vf = *(const bf16x8*)&V_[vread[dt][ch]];
        O[dt] = mfma16(vf, pf, O[dt]);
      }
    }
    // no trailing barrier: next iter writes the other buffer
  }

  // final denominator reduce (once) + store AO[b][p][c]
  float l = lsum0 + lsum1;
  l += __shfl_xor(l, 16);
  l += __shfl_xor(l, 32);
  float inv = 1.0f / l;
  const int p = q0 + w * 16 + ln;
#pragma unroll
  for (int dt = 0; dt < 2; ++dt) {
    bf16x4 ov = {(bf16_t)(O[dt][0] * inv), (bf16_t)(O[dt][1] * inv),
                 (bf16_t)(O[dt][2] * inv), (bf16_t)(O[dt][3] * inv)};
    *(bf16x4*)(AO + ((size_t)b * HW + p) * NC + h * 32 + dt * 16 + hi * 4) = ov;
  }
}

// ---------------- kernel 3: output projection ----------------
// grid (64 p-tiles, 4 o-tiles, 2 b), block 256
__global__ __launch_bounds__(256) void proj_out(
    const bf16_t* __restrict__ AO, const bf16_t* __restrict__ Wo,
    const float* __restrict__ bo, float* __restrict__ out) {
  const int p0 = blockIdx.x * 64;
  const int o0 = blockIdx.y * 64;
  const int b  = blockIdx.z;
  const int tid = threadIdx.x;
  const int w = tid >> 6, lane = tid & 63;
  const int ln = lane & 15, hi = lane >> 4;

  f32x4 acc[4] = {};
  for (int c0 = 0; c0 < NC; c0 += 32) {
    bf16x8 aw = *(const bf16x8*)(Wo + (size_t)(o0 + w * 16 + ln) * NC + c0 + hi * 8);
#pragma unroll
    for (int t = 0; t < 4; ++t) {
      bf16x8 bfr = *(const bf16x8*)(AO + ((size_t)b * HW + p0 + t * 16 + ln) * NC + c0 + hi * 8);
      acc[t] = mfma16(aw, bfr, acc[t]);
    }
  }
#pragma unroll
  for (int t = 0; t < 4; ++t) {
#pragma unroll
    for (int r = 0; r < 4; ++r) {
      int o = o0 + w * 16 + hi * 4 + r;
      out[((size_t)b * NC + o) * HW + p0 + t * 16 + ln] = acc[t][r] + bo[o];
    }
  }
}

// ---------------- launch ----------------
extern "C" void kernel_launch(void* const* d_in, const int* in_sizes, int n_in,
                              void* d_out, int out_size, void* d_ws, size_t ws_size,
                              hipStream_t stream) {
  const float* x   = (const float*)d_in[0];
  const float* flu = (const float*)d_in[1];
  const float* Wq  = (const float*)d_in[2];
  const float* bq  = (const float*)d_in[3];
  const float* Wk  = (const float*)d_in[4];
  const float* bk  = (const float*)d_in[5];
  const float* Wv  = (const float*)d_in[6];
  const float* bv  = (const float*)d_in[7];
  const float* Wo  = (const float*)d_in[8];
  const float* bo  = (const float*)d_in[9];
  float* out = (float*)d_out;

  char* ws = (char*)d_ws;
  bf16_t* Qb = (bf16_t*)(ws);                 // [2][8][4096][32] = 4 MB
  bf16_t* Kb = (bf16_t*)(ws + (4u << 20));    // 4 MB
  bf16_t* Vb = (bf16_t*)(ws + (8u << 20));    // [2][256][4096]  = 4 MB
  bf16_t* AO = (bf16_t*)(ws + (12u << 20));   // [2][4096][256]  = 4 MB
  bf16_t* Wb = (bf16_t*)(ws + (16u << 20));   // 4 x 65536 bf16  = 512 KB

  cvt_w<<<256, 256, 0, stream>>>(Wq, Wk, Wv, Wo, Wb);
  proj_qkv<<<dim3(64, 4, 2), 256, 0, stream>>>(x, flu,
      Wb, Wb + 65536, Wb + 131072, bq, bk, bv, Qb, Kb, Vb);
  attn_fwd<<<dim3(64, 16), 256, 0, stream>>>(Qb, Kb, Vb, AO);
  proj_out<<<dim3(64, 4, 2), 256, 0, stream>>>(AO, Wb + 196608, bo, out);
}